// Round 2
// baseline (443.324 us; speedup 1.0000x reference)
//
#include <hip/hip_runtime.h>

// G[u][x] = 0.5 * c_u * cos((2x+1)*u*pi/16),  c_0 = sqrt(0.5).
// scale[u,v]*h[u,x]*h[v,y] == G[u][x]*G[v][y] -> same table for both passes.
__device__ __constant__ float G[64] = {
    0.3535533906f,  0.3535533906f,  0.3535533906f,  0.3535533906f,
    0.3535533906f,  0.3535533906f,  0.3535533906f,  0.3535533906f,

    0.4903926402f,  0.4157348062f,  0.2777851165f,  0.0975451610f,
   -0.0975451610f, -0.2777851165f, -0.4157348062f, -0.4903926402f,

    0.4619397663f,  0.1913417162f, -0.1913417162f, -0.4619397663f,
   -0.4619397663f, -0.1913417162f,  0.1913417162f,  0.4619397663f,

    0.4157348062f, -0.0975451610f, -0.4903926402f, -0.2777851165f,
    0.2777851165f,  0.4903926402f,  0.0975451610f, -0.4157348062f,

    0.3535533906f, -0.3535533906f, -0.3535533906f,  0.3535533906f,
    0.3535533906f, -0.3535533906f, -0.3535533906f,  0.3535533906f,

    0.2777851165f, -0.4903926402f,  0.0975451610f,  0.4157348062f,
   -0.4157348062f, -0.0975451610f,  0.4903926402f, -0.2777851165f,

    0.1913417162f, -0.4619397663f,  0.4619397663f, -0.1913417162f,
   -0.1913417162f,  0.4619397663f, -0.4619397663f,  0.1913417162f,

    0.0975451610f, -0.2777851165f,  0.4157348062f, -0.4903926402f,
    0.4903926402f, -0.4157348062f,  0.2777851165f, -0.0975451610f,
};

// One workgroup = one (b, h) pair = 256 DCT blocks (w = 0..255).
// Stage all 64 channel rows (64 KiB) into LDS via async global_load_lds,
// then each thread transforms its own block fully in LDS (in-place pass 1).
__global__ __launch_bounds__(256) void idct_kernel(
    const float* __restrict__ dct,
    const float* __restrict__ mean_,
    const float* __restrict__ std_,
    float* __restrict__ out)
{
    __shared__ float lds[64 * 256];  // [channel][w], 64 KiB

    const int t    = threadIdx.x;
    const int wg   = blockIdx.x;     // wg = b*256 + h
    const int h    = wg & 255;
    const int b    = wg >> 8;
    const int wave = t >> 6;
    const int lane = t & 63;

    // dct[b][c][h][w]: c-stride 65536 floats; (b,h) base:
    const float* gbase = dct + (size_t)b * 64u * 65536u + (size_t)h * 256u;

    // Async stage: wave k loads channels 16k..16k+15; one instruction per
    // channel row (64 lanes x 16 B = 1 KiB = 256 floats). LDS dest is
    // wave-uniform base + lane*16, exactly matching lds[c][0..255].
#pragma unroll
    for (int i = 0; i < 16; ++i) {
        const int c = wave * 16 + i;
        const float* src = gbase + (size_t)c * 65536u + (size_t)lane * 4u;
        __builtin_amdgcn_global_load_lds(
            (const __attribute__((address_space(1))) void*)src,
            (__attribute__((address_space(3))) void*)&lds[c * 256],
            16, 0, 0);
    }
    __syncthreads();  // compiler drains vmcnt(0) before s_barrier

    // Pass 1 (in-place): for each column v, slots {u*8+v} -> t[x][v] in
    // slots {x*8+v}. Each thread touches only its own w = t entries, and
    // column slot-sets are identical read/write -> no extra barriers.
#pragma unroll
    for (int v = 0; v < 8; ++v) {
        float dv[8];
#pragma unroll
        for (int u = 0; u < 8; ++u) {
            const int c = u * 8 + v;
            dv[u] = fmaf(lds[c * 256 + t], std_[c], mean_[c]);  // destandardize
        }
#pragma unroll
        for (int x = 0; x < 8; ++x) {
            float s = 0.0f;
#pragma unroll
            for (int u = 0; u < 8; ++u)
                s = fmaf(G[u * 8 + x], dv[u], s);
            lds[(x * 8 + v) * 256 + t] = s;
        }
    }

    // Pass 2 + epilogue (pix+128)/255 folded into one FMA, vector stores.
    const float inv255 = 1.0f / 255.0f;
    const float off128 = 128.0f / 255.0f;
    // out[b][0][8h+x][8t+y]
    const size_t obase = (size_t)b * (2048u * 2048u)
                       + (size_t)(h * 8) * 2048u + (size_t)t * 8u;

#pragma unroll
    for (int x = 0; x < 8; ++x) {
        float tv[8];
#pragma unroll
        for (int v = 0; v < 8; ++v)
            tv[v] = lds[(x * 8 + v) * 256 + t];
        float pix[8];
#pragma unroll
        for (int y = 0; y < 8; ++y) {
            float s = 0.0f;
#pragma unroll
            for (int v = 0; v < 8; ++v)
                s = fmaf(G[v * 8 + y], tv[v], s);
            pix[y] = fmaf(s, inv255, off128);
        }
        float4* o = (float4*)(out + obase + (size_t)x * 2048u);
        o[0] = make_float4(pix[0], pix[1], pix[2], pix[3]);
        o[1] = make_float4(pix[4], pix[5], pix[6], pix[7]);
    }
}

extern "C" void kernel_launch(void* const* d_in, const int* in_sizes, int n_in,
                              void* d_out, int out_size, void* d_ws, size_t ws_size,
                              hipStream_t stream) {
    const float* dct  = (const float*)d_in[0];
    const float* mean = (const float*)d_in[1];
    const float* std_ = (const float*)d_in[2];
    float* out = (float*)d_out;

    // 16 batches x 256 h-rows, one workgroup each
    const int grid = 16 * 256;  // 4096
    idct_kernel<<<grid, 256, 0, stream>>>(dct, mean, std_, out);
}